// Round 11
// baseline (7348.019 us; speedup 1.0000x reference)
//
#include <hip/hip_runtime.h>
#include <math.h>

// GraphWaveNet forward, MI355X fp32.
// Outputs depend only on skip_sum at absolute tau=63; per-layer needed output
// windows are [t0s[i], 64) (135 graph-conv timesteps vs 400 in reference);
// W_r applied BEFORE the N x N graph GEMM (linear ops commute; bias post-GEMM).
// Graph GEMM is in-place on X: X's prior value IS the residual (plain RMW,
// each element owned by one thread — NO atomics, NO split-K).
// ROUND-8: round-7 counters showed atomics cost 451MB/dispatch of memory-side
// write traffic (29B per atomic) = the whole GEMM time. Replaced with
// 256-thread (4-wave) blocks, 4x8 named-register micro, plain stores.

constexpr int NN    = 1000;   // nodes
constexpr int NP    = 1008;   // K-padded nodes (mult of 16)
constexpr int TFULL = 64;
constexpr int NBATCH= 4;
constexpr int CR    = 32;     // residual/dilation channels
constexpr int CS    = 256;    // skip channels
constexpr int CE    = 512;    // end channels
constexpr int DOUTC = 12;
constexpr int DFC   = 32;
constexpr int NL    = 8;

// ---------------------------------------------------------------- adjacency
__global__ __launch_bounds__(256)
void k_adj(const float* __restrict__ adp, const float* __restrict__ pre,
           float* __restrict__ adj)
{
  const int n = blockIdx.x;
  const int tid = threadIdx.x;
  if (n >= NN) {
    for (int m = tid; m < NN; m += 256) adj[(size_t)n * NN + m] = 0.f;
    return;
  }
  __shared__ float red[8];
  float v[4];
  float mx = 0.f;   // relu values are >= 0, so 0 is a safe identity
  #pragma unroll
  for (int j = 0; j < 4; j++) {
    int m = tid + (j << 8);
    v[j] = (m < NN) ? fmaxf(adp[(size_t)n * NN + m], 0.f) : 0.f;
    mx = fmaxf(mx, v[j]);
  }
  #pragma unroll
  for (int s = 32; s; s >>= 1) mx = fmaxf(mx, __shfl_xor(mx, s));
  if ((tid & 63) == 0) red[tid >> 6] = mx;
  __syncthreads();
  mx = fmaxf(fmaxf(red[0], red[1]), fmaxf(red[2], red[3]));
  float sum = 0.f;
  #pragma unroll
  for (int j = 0; j < 4; j++) {
    int m = tid + (j << 8);
    v[j] = (m < NN) ? __expf(v[j] - mx) : 0.f;
    sum += v[j];
  }
  #pragma unroll
  for (int s = 32; s; s >>= 1) sum += __shfl_xor(sum, s);
  if ((tid & 63) == 0) red[4 + (tid >> 6)] = sum;
  __syncthreads();
  sum = red[4] + red[5] + red[6] + red[7];
  const float inv = 1.f / sum;
  #pragma unroll
  for (int j = 0; j < 4; j++) {
    int m = tid + (j << 8);
    if (m < NN) adj[(size_t)n * NN + m] = v[j] * inv + pre[(size_t)n * NN + m];
  }
}

// ---------------------------------------------------------------- start conv
__global__ __launch_bounds__(256)
void k_start(const float* __restrict__ xin, const float* __restrict__ Wst,
             const float* __restrict__ bst, float* __restrict__ X)
{
  const int n = blockIdx.x * 256 + threadIdx.x;
  if (n >= NN) return;
  const int t = 33 + blockIdx.y;
  const int b = blockIdx.z;
  const float val = xin[((size_t)b * NN + n) * TFULL + t];
  #pragma unroll
  for (int c = 0; c < CR; c++)
    X[(((size_t)(b * CR + c)) * TFULL + t) * NN + n] = Wst[c] * val + bst[c];
}

// ------------------------------------------------------- W_e1 transpose once
__global__ __launch_bounds__(256)
void k_tr_we1(const float* __restrict__ We1, float* __restrict__ We1T)
{
  const int e = blockIdx.x;                       // 0..511
  for (int o = threadIdx.x; o < CS; o += 256)
    We1T[(size_t)o * CE + e] = We1[(size_t)e * CS + o];
}

// ------------------------------------------------- fused dilated conv + W_r
__global__ __launch_bounds__(256)
void k_point(const float* __restrict__ X, float* __restrict__ u_t,
             float* __restrict__ xc63,
             const float* __restrict__ Wf, const float* __restrict__ bf,
             const float* __restrict__ Wg, const float* __restrict__ bg,
             const float* __restrict__ Wr,
             int layer, int d, int t0, int W, int doU)
{
  const int n = blockIdx.x * 256 + threadIdx.x;
  const int tw = blockIdx.y;
  const int b = blockIdx.z;
  if (n >= NP) return;
  if (n >= NN) {                 // zero K-padding so the GEMM reads 0*0
    if (doU) {
      #pragma unroll
      for (int o = 0; o < CR; o++)
        u_t[((size_t)(b * CR + o) * W + tw) * NP + n] = 0.f;
    }
    return;
  }
  const int t = t0 + tw;
  const float* wf = Wf + (size_t)layer * CR * CR * 2;
  const float* wg = Wg + (size_t)layer * CR * CR * 2;
  const float* wr = Wr + (size_t)layer * CR * CR;
  const float* bff = bf + layer * CR;
  const float* bgg = bg + layer * CR;

  float x0[CR], x1[CR];
  #pragma unroll
  for (int c = 0; c < CR; c++) {
    const float* base = X + ((size_t)(b * CR + c) * TFULL) * NN + n;
    x0[c] = base[(size_t)(t - d) * NN];
    x1[c] = base[(size_t)t * NN];
  }
  float xc[CR];
  #pragma unroll
  for (int co = 0; co < CR; co++) {
    float f = bff[co], g = bgg[co];
    #pragma unroll
    for (int ci = 0; ci < CR; ci++) {
      const float wf0 = wf[(co * CR + ci) * 2 + 0];
      const float wf1 = wf[(co * CR + ci) * 2 + 1];
      const float wg0 = wg[(co * CR + ci) * 2 + 0];
      const float wg1 = wg[(co * CR + ci) * 2 + 1];
      f = fmaf(wf0, x0[ci], f); f = fmaf(wf1, x1[ci], f);
      g = fmaf(wg0, x0[ci], g); g = fmaf(wg1, x1[ci], g);
    }
    // exact identities: tanh(f) = 1 - 2/(e^{2f}+1); sigmoid via expf
    const float th = 1.f - 2.f / (__expf(2.f * f) + 1.f);
    const float sg = 1.f / (1.f + __expf(-g));
    xc[co] = th * sg;
  }
  if (doU) {
    #pragma unroll
    for (int o = 0; o < CR; o++) {
      float u = 0.f;
      #pragma unroll
      for (int c = 0; c < CR; c++) u = fmaf(wr[o * CR + c], xc[c], u);
      u_t[((size_t)(b * CR + o) * W + tw) * NP + n] = u;
    }
  }
  if (t == TFULL - 1) {
    #pragma unroll
    for (int c = 0; c < CR; c++) xc63[(size_t)(b * CR + c) * NN + n] = xc[c];
  }
}

// ------------------------------------------------------------- skip accumul.
__global__ __launch_bounds__(256)
void k_skip(const float* __restrict__ xc63, const float* __restrict__ Wsk,
            const float* __restrict__ bsk, float* __restrict__ skip, int layer)
{
  const int nl = threadIdx.x & 63;
  const int og = threadIdx.x >> 6;            // 0..3 (wave-uniform)
  const int n = blockIdx.x * 64 + nl;
  const int b = blockIdx.y;
  if (n >= NN) return;
  float xc[CR];
  #pragma unroll
  for (int c = 0; c < CR; c++) xc[c] = xc63[(size_t)(b * CR + c) * NN + n];
  const float* w = Wsk + (size_t)layer * CS * CR;
  const float* bb = bsk + layer * CS;
  float* sp = skip + ((size_t)b * NN + n) * CS;
  #pragma unroll
  for (int j4 = 0; j4 < 16; j4++) {
    const int o0 = og * 64 + j4 * 4;
    float a[4];
    #pragma unroll
    for (int k = 0; k < 4; k++) {
      const int o = o0 + k;
      float s = bb[o];
      #pragma unroll
      for (int c = 0; c < CR; c++) s = fmaf(w[o * CR + c], xc[c], s);
      a[k] = s;
    }
    float4 res = make_float4(a[0], a[1], a[2], a[3]);
    if (layer > 0) {
      const float4 old = *(const float4*)(sp + o0);
      res.x += old.x; res.y += old.y; res.z += old.z; res.w += old.w;
    }
    *(float4*)(sp + o0) = res;
  }
}

// ------------------------------------------------------------------- GEMM
// C = A[M,K] * B[K,cols]. 64x128 tile, 256 threads (4 waves), 4x8 micro.
// Accumulator: 8 NAMED float4 — no indexable locals -> guaranteed registers.
// Double-buffered LDS, one barrier per 16-wide K-tile, full K per block.
// 1-D grid with bijective XCD-chunked map (adj panel L2 locality).
// MODE 0 (graph): row=(b*32+c)*W+tw -> X[(bc*64+t0+tw)*NN+col]
//                 = acc + b_r[bc&31] + X[same]  (in-place residual, plain RMW)
// MODE 1 (head):  C[row*ncols+col] = relu(acc + bias[col]), guard row<M.
#define FMA4(Cv, s, Vv) \
  Cv.x = fmaf(s, Vv.x, Cv.x); Cv.y = fmaf(s, Vv.y, Cv.y); \
  Cv.z = fmaf(s, Vv.z, Cv.z); Cv.w = fmaf(s, Vv.w, Cv.w)

template<int MODE>
__global__ __launch_bounds__(256, 4)
void k_gemm(const float* __restrict__ A, const float* __restrict__ Bm,
            float* __restrict__ C, const float* __restrict__ bias,
            int M, int K, int sA, int sB, int ncols,
            int W, int t0, int NR, int NC)
{
  // bijective XCD-chunked mapping: xcd = bid&7 gets a contiguous work range
  const int T = NR * NC;
  const int xcd = blockIdx.x & 7, pos = blockIdx.x >> 3;
  const int q = T >> 3, r = T & 7;
  const int work = (xcd < r) ? (xcd * (q + 1) + pos) : (r + xcd * q + pos);
  const int rb = work % NR;
  const int ct = work / NR;

  const int ctile = ct * 128;
  const int row0  = rb * 64;

  __shared__ float As[2][16][68];    // +4 pad: conflict-free frag reads
  __shared__ float Bs[2][16][132];
  const int tid = threadIdx.x;

  // staging indices (256 thr): A 64x16: one float4/thread along k.
  //                            B 16x128: two float4/thread along cols.
  const int a_r = tid >> 2;            // 0..63
  const int a_k = (tid & 3) << 2;      // 0,4,8,12
  const int b_k = tid >> 4;            // 0..15
  const int b_c = (tid & 15) << 3;     // 0..120
  // fragment indices: 16x16 thread grid, each 4 rows x 8 cols
  const int rf = (tid & 15) << 2;      // 0..60
  const int cf = (tid >> 4) << 3;      // 0..120

  const float4 z4 = make_float4(0.f, 0.f, 0.f, 0.f);
  float4 C00 = z4, C01 = z4, C10 = z4, C11 = z4;
  float4 C20 = z4, C21 = z4, C30 = z4, C31 = z4;

  const int arow = row0 + a_r;
  const bool aok = (arow < M);
  const float* ap = A + (size_t)arow * sA + a_k;
  const int bcol = ctile + b_c;
  const bool bok = (bcol < ncols);     // ncols % 8 == 0: covers both float4s
  const float* bp = Bm + (size_t)b_k * sB + bcol;

  float4 av, bv0, bv1;
  av  = aok ? *(const float4*)(ap)     : z4;
  bv0 = bok ? *(const float4*)(bp)     : z4;
  bv1 = bok ? *(const float4*)(bp + 4) : z4;
  As[0][a_k + 0][a_r] = av.x; As[0][a_k + 1][a_r] = av.y;
  As[0][a_k + 2][a_r] = av.z; As[0][a_k + 3][a_r] = av.w;
  *(float4*)&Bs[0][b_k][b_c]     = bv0;
  *(float4*)&Bs[0][b_k][b_c + 4] = bv1;
  __syncthreads();

  const int nkt = K >> 4;
  for (int kt = 0; kt < nkt; kt++) {
    const int buf = kt & 1;
    const bool more = (kt + 1 < nkt);
    if (more) {
      const int k0 = (kt + 1) << 4;
      av  = aok ? *(const float4*)(ap + k0) : z4;
      const float* bq = bp + (size_t)k0 * sB;
      bv0 = bok ? *(const float4*)(bq)     : z4;
      bv1 = bok ? *(const float4*)(bq + 4) : z4;
    }
    #pragma unroll
    for (int k = 0; k < 16; k++) {
      const float4 A0 = *(const float4*)&As[buf][k][rf];
      const float4 B0 = *(const float4*)&Bs[buf][k][cf];
      const float4 B1 = *(const float4*)&Bs[buf][k][cf + 4];
      FMA4(C00, A0.x, B0); FMA4(C01, A0.x, B1);
      FMA4(C10, A0.y, B0); FMA4(C11, A0.y, B1);
      FMA4(C20, A0.z, B0); FMA4(C21, A0.z, B1);
      FMA4(C30, A0.w, B0); FMA4(C31, A0.w, B1);
    }
    if (more) {
      const int nb = buf ^ 1;
      // single-barrier double buffer: all reads of nb's old contents ended
      // at the barrier closing iteration kt-1
      As[nb][a_k + 0][a_r] = av.x; As[nb][a_k + 1][a_r] = av.y;
      As[nb][a_k + 2][a_r] = av.z; As[nb][a_k + 3][a_r] = av.w;
      *(float4*)&Bs[nb][b_k][b_c]     = bv0;
      *(float4*)&Bs[nb][b_k][b_c + 4] = bv1;
      __syncthreads();
    }
  }

  // epilogue — named accumulators, plain stores (one owner per element)
#define EPI_G(j, CA, CB) { \
    const int row = row0 + rf + (j); \
    const int bc = row / W; \
    const int tw = row - bc * W; \
    const float add = bias[bc & (CR - 1)]; \
    if (ctile + cf < ncols) { \
      float* cp = C + ((size_t)bc * TFULL + t0 + tw) * NN + ctile + cf; \
      float4 o0 = *(const float4*)(cp); \
      float4 o1 = *(const float4*)(cp + 4); \
      o0.x += CA.x + add; o0.y += CA.y + add; \
      o0.z += CA.z + add; o0.w += CA.w + add; \
      o1.x += CB.x + add; o1.y += CB.y + add; \
      o1.z += CB.z + add; o1.w += CB.w + add; \
      *(float4*)(cp) = o0; *(float4*)(cp + 4) = o1; \
    } }
#define EPI_H(j, CA, CB) { \
    const int row = row0 + rf + (j); \
    if (row < M) { \
      float* cp = C + (size_t)row * ncols + ctile + cf; \
      const float4 s0 = *(const float4*)(bias + ctile + cf); \
      const float4 s1 = *(const float4*)(bias + ctile + cf + 4); \
      float4 o0, o1; \
      o0.x = fmaxf(CA.x + s0.x, 0.f); o0.y = fmaxf(CA.y + s0.y, 0.f); \
      o0.z = fmaxf(CA.z + s0.z, 0.f); o0.w = fmaxf(CA.w + s0.w, 0.f); \
      o1.x = fmaxf(CB.x + s1.x, 0.f); o1.y = fmaxf(CB.y + s1.y, 0.f); \
      o1.z = fmaxf(CB.z + s1.z, 0.f); o1.w = fmaxf(CB.w + s1.w, 0.f); \
      *(float4*)(cp) = o0; *(float4*)(cp + 4) = o1; \
    } }

  if (MODE == 0) {
    EPI_G(0, C00, C01); EPI_G(1, C10, C11);
    EPI_G(2, C20, C21); EPI_G(3, C30, C31);
  } else {
    EPI_H(0, C00, C01); EPI_H(1, C10, C11);
    EPI_H(2, C20, C21); EPI_H(3, C30, C31);
  }
#undef EPI_G
#undef EPI_H
}

// ------------------------------------------------------- head stage 1
__global__ __launch_bounds__(256)
void k_h2a(const float* __restrict__ feat, const float* __restrict__ We2,
           const float* __restrict__ Wfp, float* __restrict__ part)
{
  const int bn = blockIdx.x * 256 + threadIdx.x;
  const int p = blockIdx.y;                     // 0..7
  if (bn >= NBATCH * NN) return;
  float f[64];
  const float* fp = feat + (size_t)bn * CE + p * 64;
  #pragma unroll
  for (int e4 = 0; e4 < 64; e4 += 4) {
    const float4 v = *(const float4*)(fp + e4);
    f[e4]     = v.x; f[e4 + 1] = v.y;
    f[e4 + 2] = v.z; f[e4 + 3] = v.w;
  }
  float ay[DOUTC], af[DFC];
  #pragma unroll
  for (int j = 0; j < DOUTC; j++) ay[j] = 0.f;
  #pragma unroll
  for (int j = 0; j < DFC; j++) af[j] = 0.f;
  const int e0 = p * 64;
  #pragma unroll
  for (int e = 0; e < 64; e++) {
    const float fe = f[e];
    #pragma unroll
    for (int j = 0; j < DOUTC; j++)
      ay[j] = fmaf(We2[(size_t)j * CE + e0 + e], fe, ay[j]);
    #pragma unroll
    for (int j = 0; j < DFC; j++)
      af[j] = fmaf(Wfp[(size_t)j * CE + e0 + e], fe, af[j]);
  }
  #pragma unroll
  for (int j = 0; j < DOUTC; j++) part[((size_t)p * 44 + j) * 4096 + bn] = ay[j];
  #pragma unroll
  for (int j = 0; j < DFC; j++)
    part[((size_t)p * 44 + 12 + j) * 4096 + bn] = af[j];
}

// ------------------------------------------------------- head stage 2
__global__ __launch_bounds__(256)
void k_h2b(const float* __restrict__ part, const float* __restrict__ be2,
           const float* __restrict__ bfp, float* __restrict__ out)
{
  const int bn = blockIdx.x * 256 + threadIdx.x;
  const int j = blockIdx.y;                     // 0..43
  if (bn >= NBATCH * NN) return;
  float s = (j < DOUTC) ? be2[j] : bfp[j - DOUTC];
  #pragma unroll
  for (int p = 0; p < 8; p++) s += part[((size_t)p * 44 + j) * 4096 + bn];
  if (j < DOUTC) out[(size_t)bn * DOUTC + j] = s;
  else out[(size_t)NBATCH * NN * DOUTC + (size_t)bn * DFC + (j - DOUTC)] = s;
}

// ------------------------------------------------------------------ launch
extern "C" void kernel_launch(void* const* d_in, const int* in_sizes, int n_in,
                              void* d_out, int out_size, void* d_ws, size_t ws_size,
                              hipStream_t stream)
{
  const float* xin = (const float*)d_in[0];
  const float* pre = (const float*)d_in[1];
  const float* adp = (const float*)d_in[2];
  const float* Wst = (const float*)d_in[3];
  const float* bst = (const float*)d_in[4];
  const float* Wf  = (const float*)d_in[5];
  const float* bf  = (const float*)d_in[6];
  const float* Wg  = (const float*)d_in[7];
  const float* bg  = (const float*)d_in[8];
  const float* Wr  = (const float*)d_in[9];
  const float* br  = (const float*)d_in[10];
  const float* Wsk = (const float*)d_in[11];
  const float* bsk = (const float*)d_in[12];
  const float* We1 = (const float*)d_in[13];
  const float* be1 = (const float*)d_in[14];
  const float* We2 = (const float*)d_in[15];
  const float* be2 = (const float*)d_in[16];
  const float* Wfp = (const float*)d_in[17];
  const float* bfp = (const float*)d_in[18];
  float* out = (float*)d_out;

  // workspace layout (floats); total 16,401,792 floats = 62.6 MiB
  float* ws    = (float*)d_ws;
  float* adj   = ws;                                   // 1008*1000
  float* X     = adj   + (size_t)NP * NN;              // 128*64*1000
  float* u_t   = X     + (size_t)128 * TFULL * NN;     // 128*30*1008
  float* xc63  = u_t   + (size_t)128 * 30 * NP;        // 128*1000
  float* skip  = xc63  + (size_t)128 * NN;             // 4000*256
  float* feat2 = skip  + (size_t)NBATCH * NN * CS;     // 4000*512
  float* We1T  = feat2 + (size_t)NBATCH * NN * CE;     // 256*512
  float* part  = u_t;  // head partials (8*44*4096 = 1.44M floats) alias u_t

  k_adj<<<dim3(NP), dim3(256), 0, stream>>>(adp, pre, adj);
  k_start<<<dim3(4, 31, NBATCH), dim3(256), 0, stream>>>(xin, Wst, bst, X);
  k_tr_we1<<<dim3(CE), dim3(256), 0, stream>>>(We1, We1T);

  const int dil[NL] = {1, 2, 4, 8, 1, 2, 4, 8};
  const int t0s[NL] = {34, 36, 40, 48, 49, 51, 55, 63}; // needed out-windows

  for (int i = 0; i < NL; i++) {
    const int d = dil[i], t0 = t0s[i], W = TFULL - t0;
    const int doU = (i < NL - 1) ? 1 : 0;   // layer 7: skip path only
    k_point<<<dim3(4, W, NBATCH), dim3(256), 0, stream>>>(
        X, u_t, xc63, Wf, bf, Wg, bg, Wr, i, d, t0, W, doU);
    k_skip<<<dim3(16, NBATCH), dim3(256), 0, stream>>>(xc63, Wsk, bsk, skip, i);
    if (doU) {
      const int M = 128 * W;
      const int NR = 2 * W, NC = 8;
      k_gemm<0><<<dim3(NR * NC), dim3(256), 0, stream>>>(
          u_t, adj, X, br + i * CR, M, NP, NP, NN, NN, W, t0, NR, NC);
    }
  }

  // head: feat2 = relu(skip @ We1^T + be1)  [4000 x 512]
  {
    const int NR = 63, NC = 4;
    k_gemm<1><<<dim3(NR * NC), dim3(256), 0, stream>>>(
        skip, We1T, feat2, be1, NBATCH * NN, CS, CS, CE, CE, 1, 0, NR, NC);
  }
  k_h2a<<<dim3(16, 8), dim3(256), 0, stream>>>(feat2, We2, Wfp, part);
  k_h2b<<<dim3(16, 44), dim3(256), 0, stream>>>(part, be2, bfp, out);
}

// Round 13
// 1826.900 us; speedup vs baseline: 4.0221x; 4.0221x over previous
//
#include <hip/hip_runtime.h>
#include <math.h>

// GraphWaveNet forward, MI355X fp32.
// Outputs depend only on skip_sum at absolute tau=63; per-layer needed output
// windows are [t0s[i], 64) (135 graph-conv timesteps vs 400 in reference);
// W_r applied BEFORE the N x N graph GEMM (linear ops commute; bias post-GEMM).
// Graph GEMM is in-place on X: X's prior value IS the residual (plain RMW,
// each element owned by one thread — NO atomics, NO split-K).
// ROUND-12 FIX: round-11 counters showed __launch_bounds__(256,4) capped
// VGPR at 64 -> the 8 named-float4 accumulators spilled to scratch
// (WRITE_SIZE 3.77GB/dispatch, VALUBusy 4.9%). Loosened to (256,2):
// VGPR cap 256, kernel wants ~84 (r3/r6 measured) -> no spill, occupancy
// still ~4 blocks/CU from actual usage (LDS 25.6KB caps at 6).

constexpr int NN    = 1000;   // nodes
constexpr int NP    = 1008;   // K-padded nodes (mult of 16)
constexpr int TFULL = 64;
constexpr int NBATCH= 4;
constexpr int CR    = 32;     // residual/dilation channels
constexpr int CS    = 256;    // skip channels
constexpr int CE    = 512;    // end channels
constexpr int DOUTC = 12;
constexpr int DFC   = 32;
constexpr int NL    = 8;

// ---------------------------------------------------------------- adjacency
__global__ __launch_bounds__(256)
void k_adj(const float* __restrict__ adp, const float* __restrict__ pre,
           float* __restrict__ adj)
{
  const int n = blockIdx.x;
  const int tid = threadIdx.x;
  if (n >= NN) {
    for (int m = tid; m < NN; m += 256) adj[(size_t)n * NN + m] = 0.f;
    return;
  }
  __shared__ float red[8];
  float v[4];
  float mx = 0.f;   // relu values are >= 0, so 0 is a safe identity
  #pragma unroll
  for (int j = 0; j < 4; j++) {
    int m = tid + (j << 8);
    v[j] = (m < NN) ? fmaxf(adp[(size_t)n * NN + m], 0.f) : 0.f;
    mx = fmaxf(mx, v[j]);
  }
  #pragma unroll
  for (int s = 32; s; s >>= 1) mx = fmaxf(mx, __shfl_xor(mx, s));
  if ((tid & 63) == 0) red[tid >> 6] = mx;
  __syncthreads();
  mx = fmaxf(fmaxf(red[0], red[1]), fmaxf(red[2], red[3]));
  float sum = 0.f;
  #pragma unroll
  for (int j = 0; j < 4; j++) {
    int m = tid + (j << 8);
    v[j] = (m < NN) ? __expf(v[j] - mx) : 0.f;
    sum += v[j];
  }
  #pragma unroll
  for (int s = 32; s; s >>= 1) sum += __shfl_xor(sum, s);
  if ((tid & 63) == 0) red[4 + (tid >> 6)] = sum;
  __syncthreads();
  sum = red[4] + red[5] + red[6] + red[7];
  const float inv = 1.f / sum;
  #pragma unroll
  for (int j = 0; j < 4; j++) {
    int m = tid + (j << 8);
    if (m < NN) adj[(size_t)n * NN + m] = v[j] * inv + pre[(size_t)n * NN + m];
  }
}

// ---------------------------------------------------------------- start conv
__global__ __launch_bounds__(256)
void k_start(const float* __restrict__ xin, const float* __restrict__ Wst,
             const float* __restrict__ bst, float* __restrict__ X)
{
  const int n = blockIdx.x * 256 + threadIdx.x;
  if (n >= NN) return;
  const int t = 33 + blockIdx.y;
  const int b = blockIdx.z;
  const float val = xin[((size_t)b * NN + n) * TFULL + t];
  #pragma unroll
  for (int c = 0; c < CR; c++)
    X[(((size_t)(b * CR + c)) * TFULL + t) * NN + n] = Wst[c] * val + bst[c];
}

// ------------------------------------------------------- W_e1 transpose once
__global__ __launch_bounds__(256)
void k_tr_we1(const float* __restrict__ We1, float* __restrict__ We1T)
{
  const int e = blockIdx.x;                       // 0..511
  for (int o = threadIdx.x; o < CS; o += 256)
    We1T[(size_t)o * CE + e] = We1[(size_t)e * CS + o];
}

// ------------------------------------------------- fused dilated conv + W_r
__global__ __launch_bounds__(256)
void k_point(const float* __restrict__ X, float* __restrict__ u_t,
             float* __restrict__ xc63,
             const float* __restrict__ Wf, const float* __restrict__ bf,
             const float* __restrict__ Wg, const float* __restrict__ bg,
             const float* __restrict__ Wr,
             int layer, int d, int t0, int W, int doU)
{
  const int n = blockIdx.x * 256 + threadIdx.x;
  const int tw = blockIdx.y;
  const int b = blockIdx.z;
  if (n >= NP) return;
  if (n >= NN) {                 // zero K-padding so the GEMM reads 0*0
    if (doU) {
      #pragma unroll
      for (int o = 0; o < CR; o++)
        u_t[((size_t)(b * CR + o) * W + tw) * NP + n] = 0.f;
    }
    return;
  }
  const int t = t0 + tw;
  const float* wf = Wf + (size_t)layer * CR * CR * 2;
  const float* wg = Wg + (size_t)layer * CR * CR * 2;
  const float* wr = Wr + (size_t)layer * CR * CR;
  const float* bff = bf + layer * CR;
  const float* bgg = bg + layer * CR;

  float x0[CR], x1[CR];
  #pragma unroll
  for (int c = 0; c < CR; c++) {
    const float* base = X + ((size_t)(b * CR + c) * TFULL) * NN + n;
    x0[c] = base[(size_t)(t - d) * NN];
    x1[c] = base[(size_t)t * NN];
  }
  float xc[CR];
  #pragma unroll
  for (int co = 0; co < CR; co++) {
    float f = bff[co], g = bgg[co];
    #pragma unroll
    for (int ci = 0; ci < CR; ci++) {
      const float wf0 = wf[(co * CR + ci) * 2 + 0];
      const float wf1 = wf[(co * CR + ci) * 2 + 1];
      const float wg0 = wg[(co * CR + ci) * 2 + 0];
      const float wg1 = wg[(co * CR + ci) * 2 + 1];
      f = fmaf(wf0, x0[ci], f); f = fmaf(wf1, x1[ci], f);
      g = fmaf(wg0, x0[ci], g); g = fmaf(wg1, x1[ci], g);
    }
    // exact identities: tanh(f) = 1 - 2/(e^{2f}+1); sigmoid via expf
    const float th = 1.f - 2.f / (__expf(2.f * f) + 1.f);
    const float sg = 1.f / (1.f + __expf(-g));
    xc[co] = th * sg;
  }
  if (doU) {
    #pragma unroll
    for (int o = 0; o < CR; o++) {
      float u = 0.f;
      #pragma unroll
      for (int c = 0; c < CR; c++) u = fmaf(wr[o * CR + c], xc[c], u);
      u_t[((size_t)(b * CR + o) * W + tw) * NP + n] = u;
    }
  }
  if (t == TFULL - 1) {
    #pragma unroll
    for (int c = 0; c < CR; c++) xc63[(size_t)(b * CR + c) * NN + n] = xc[c];
  }
}

// ------------------------------------------------------------- skip accumul.
__global__ __launch_bounds__(256)
void k_skip(const float* __restrict__ xc63, const float* __restrict__ Wsk,
            const float* __restrict__ bsk, float* __restrict__ skip, int layer)
{
  const int nl = threadIdx.x & 63;
  const int og = threadIdx.x >> 6;            // 0..3 (wave-uniform)
  const int n = blockIdx.x * 64 + nl;
  const int b = blockIdx.y;
  if (n >= NN) return;
  float xc[CR];
  #pragma unroll
  for (int c = 0; c < CR; c++) xc[c] = xc63[(size_t)(b * CR + c) * NN + n];
  const float* w = Wsk + (size_t)layer * CS * CR;
  const float* bb = bsk + layer * CS;
  float* sp = skip + ((size_t)b * NN + n) * CS;
  #pragma unroll
  for (int j4 = 0; j4 < 16; j4++) {
    const int o0 = og * 64 + j4 * 4;
    float a[4];
    #pragma unroll
    for (int k = 0; k < 4; k++) {
      const int o = o0 + k;
      float s = bb[o];
      #pragma unroll
      for (int c = 0; c < CR; c++) s = fmaf(w[o * CR + c], xc[c], s);
      a[k] = s;
    }
    float4 res = make_float4(a[0], a[1], a[2], a[3]);
    if (layer > 0) {
      const float4 old = *(const float4*)(sp + o0);
      res.x += old.x; res.y += old.y; res.z += old.z; res.w += old.w;
    }
    *(float4*)(sp + o0) = res;
  }
}

// ------------------------------------------------------------------- GEMM
// C = A[M,K] * B[K,cols]. 64x128 tile, 256 threads (4 waves), 4x8 micro.
// Accumulator: 8 NAMED float4 — no indexable locals -> guaranteed registers.
// __launch_bounds__(256,2): VGPR cap 256 (kernel wants ~84) -> NO spill.
// Double-buffered LDS, one barrier per 16-wide K-tile, full K per block.
// 1-D grid with bijective XCD-chunked map (adj panel L2 locality).
// MODE 0 (graph): row=(b*32+c)*W+tw -> X[(bc*64+t0+tw)*NN+col]
//                 = acc + b_r[bc&31] + X[same]  (in-place residual, plain RMW)
// MODE 1 (head):  C[row*ncols+col] = relu(acc + bias[col]), guard row<M.
#define FMA4(Cv, s, Vv) \
  Cv.x = fmaf(s, Vv.x, Cv.x); Cv.y = fmaf(s, Vv.y, Cv.y); \
  Cv.z = fmaf(s, Vv.z, Cv.z); Cv.w = fmaf(s, Vv.w, Cv.w)

template<int MODE>
__global__ __launch_bounds__(256, 2)
void k_gemm(const float* __restrict__ A, const float* __restrict__ Bm,
            float* __restrict__ C, const float* __restrict__ bias,
            int M, int K, int sA, int sB, int ncols,
            int W, int t0, int NR, int NC)
{
  // bijective XCD-chunked mapping: xcd = bid&7 gets a contiguous work range
  const int T = NR * NC;
  const int xcd = blockIdx.x & 7, pos = blockIdx.x >> 3;
  const int q = T >> 3, r = T & 7;
  const int work = (xcd < r) ? (xcd * (q + 1) + pos) : (r + xcd * q + pos);
  const int rb = work % NR;
  const int ct = work / NR;

  const int ctile = ct * 128;
  const int row0  = rb * 64;

  __shared__ float As[2][16][68];    // +4 pad: conflict-free frag reads
  __shared__ float Bs[2][16][132];
  const int tid = threadIdx.x;

  // staging indices (256 thr): A 64x16: one float4/thread along k.
  //                            B 16x128: two float4/thread along cols.
  const int a_r = tid >> 2;            // 0..63
  const int a_k = (tid & 3) << 2;      // 0,4,8,12
  const int b_k = tid >> 4;            // 0..15
  const int b_c = (tid & 15) << 3;     // 0..120
  // fragment indices: 16x16 thread grid, each 4 rows x 8 cols
  const int rf = (tid & 15) << 2;      // 0..60
  const int cf = (tid >> 4) << 3;      // 0..120

  const float4 z4 = make_float4(0.f, 0.f, 0.f, 0.f);
  float4 C00 = z4, C01 = z4, C10 = z4, C11 = z4;
  float4 C20 = z4, C21 = z4, C30 = z4, C31 = z4;

  const int arow = row0 + a_r;
  const bool aok = (arow < M);
  const float* ap = A + (size_t)arow * sA + a_k;
  const int bcol = ctile + b_c;
  const bool bok = (bcol < ncols);     // ncols % 8 == 0: covers both float4s
  const float* bp = Bm + (size_t)b_k * sB + bcol;

  float4 av, bv0, bv1;
  av  = aok ? *(const float4*)(ap)     : z4;
  bv0 = bok ? *(const float4*)(bp)     : z4;
  bv1 = bok ? *(const float4*)(bp + 4) : z4;
  As[0][a_k + 0][a_r] = av.x; As[0][a_k + 1][a_r] = av.y;
  As[0][a_k + 2][a_r] = av.z; As[0][a_k + 3][a_r] = av.w;
  *(float4*)&Bs[0][b_k][b_c]     = bv0;
  *(float4*)&Bs[0][b_k][b_c + 4] = bv1;
  __syncthreads();

  const int nkt = K >> 4;
  for (int kt = 0; kt < nkt; kt++) {
    const int buf = kt & 1;
    const bool more = (kt + 1 < nkt);
    if (more) {
      const int k0 = (kt + 1) << 4;
      av  = aok ? *(const float4*)(ap + k0) : z4;
      const float* bq = bp + (size_t)k0 * sB;
      bv0 = bok ? *(const float4*)(bq)     : z4;
      bv1 = bok ? *(const float4*)(bq + 4) : z4;
    }
    #pragma unroll
    for (int k = 0; k < 16; k++) {
      const float4 A0 = *(const float4*)&As[buf][k][rf];
      const float4 B0 = *(const float4*)&Bs[buf][k][cf];
      const float4 B1 = *(const float4*)&Bs[buf][k][cf + 4];
      FMA4(C00, A0.x, B0); FMA4(C01, A0.x, B1);
      FMA4(C10, A0.y, B0); FMA4(C11, A0.y, B1);
      FMA4(C20, A0.z, B0); FMA4(C21, A0.z, B1);
      FMA4(C30, A0.w, B0); FMA4(C31, A0.w, B1);
    }
    if (more) {
      const int nb = buf ^ 1;
      // single-barrier double buffer: all reads of nb's old contents ended
      // at the barrier closing iteration kt-1
      As[nb][a_k + 0][a_r] = av.x; As[nb][a_k + 1][a_r] = av.y;
      As[nb][a_k + 2][a_r] = av.z; As[nb][a_k + 3][a_r] = av.w;
      *(float4*)&Bs[nb][b_k][b_c]     = bv0;
      *(float4*)&Bs[nb][b_k][b_c + 4] = bv1;
      __syncthreads();
    }
  }

  // epilogue — named accumulators, plain stores (one owner per element)
#define EPI_G(j, CA, CB) { \
    const int row = row0 + rf + (j); \
    const int bc = row / W; \
    const int tw = row - bc * W; \
    const float add = bias[bc & (CR - 1)]; \
    if (ctile + cf < ncols) { \
      float* cp = C + ((size_t)bc * TFULL + t0 + tw) * NN + ctile + cf; \
      float4 o0 = *(const float4*)(cp); \
      float4 o1 = *(const float4*)(cp + 4); \
      o0.x += CA.x + add; o0.y += CA.y + add; \
      o0.z += CA.z + add; o0.w += CA.w + add; \
      o1.x += CB.x + add; o1.y += CB.y + add; \
      o1.z += CB.z + add; o1.w += CB.w + add; \
      *(float4*)(cp) = o0; *(float4*)(cp + 4) = o1; \
    } }
#define EPI_H(j, CA, CB) { \
    const int row = row0 + rf + (j); \
    if (row < M) { \
      float* cp = C + (size_t)row * ncols + ctile + cf; \
      const float4 s0 = *(const float4*)(bias + ctile + cf); \
      const float4 s1 = *(const float4*)(bias + ctile + cf + 4); \
      float4 o0, o1; \
      o0.x = fmaxf(CA.x + s0.x, 0.f); o0.y = fmaxf(CA.y + s0.y, 0.f); \
      o0.z = fmaxf(CA.z + s0.z, 0.f); o0.w = fmaxf(CA.w + s0.w, 0.f); \
      o1.x = fmaxf(CB.x + s1.x, 0.f); o1.y = fmaxf(CB.y + s1.y, 0.f); \
      o1.z = fmaxf(CB.z + s1.z, 0.f); o1.w = fmaxf(CB.w + s1.w, 0.f); \
      *(float4*)(cp) = o0; *(float4*)(cp + 4) = o1; \
    } }

  if (MODE == 0) {
    EPI_G(0, C00, C01); EPI_G(1, C10, C11);
    EPI_G(2, C20, C21); EPI_G(3, C30, C31);
  } else {
    EPI_H(0, C00, C01); EPI_H(1, C10, C11);
    EPI_H(2, C20, C21); EPI_H(3, C30, C31);
  }
#undef EPI_G
#undef EPI_H
}

// ------------------------------------------------------- head stage 1
__global__ __launch_bounds__(256)
void k_h2a(const float* __restrict__ feat, const float* __restrict__ We2,
           const float* __restrict__ Wfp, float* __restrict__ part)
{
  const int bn = blockIdx.x * 256 + threadIdx.x;
  const int p = blockIdx.y;                     // 0..7
  if (bn >= NBATCH * NN) return;
  float f[64];
  const float* fp = feat + (size_t)bn * CE + p * 64;
  #pragma unroll
  for (int e4 = 0; e4 < 64; e4 += 4) {
    const float4 v = *(const float4*)(fp + e4);
    f[e4]     = v.x; f[e4 + 1] = v.y;
    f[e4 + 2] = v.z; f[e4 + 3] = v.w;
  }
  float ay[DOUTC], af[DFC];
  #pragma unroll
  for (int j = 0; j < DOUTC; j++) ay[j] = 0.f;
  #pragma unroll
  for (int j = 0; j < DFC; j++) af[j] = 0.f;
  const int e0 = p * 64;
  #pragma unroll
  for (int e = 0; e < 64; e++) {
    const float fe = f[e];
    #pragma unroll
    for (int j = 0; j < DOUTC; j++)
      ay[j] = fmaf(We2[(size_t)j * CE + e0 + e], fe, ay[j]);
    #pragma unroll
    for (int j = 0; j < DFC; j++)
      af[j] = fmaf(Wfp[(size_t)j * CE + e0 + e], fe, af[j]);
  }
  #pragma unroll
  for (int j = 0; j < DOUTC; j++) part[((size_t)p * 44 + j) * 4096 + bn] = ay[j];
  #pragma unroll
  for (int j = 0; j < DFC; j++)
    part[((size_t)p * 44 + 12 + j) * 4096 + bn] = af[j];
}

// ------------------------------------------------------- head stage 2
__global__ __launch_bounds__(256)
void k_h2b(const float* __restrict__ part, const float* __restrict__ be2,
           const float* __restrict__ bfp, float* __restrict__ out)
{
  const int bn = blockIdx.x * 256 + threadIdx.x;
  const int j = blockIdx.y;                     // 0..43
  if (bn >= NBATCH * NN) return;
  float s = (j < DOUTC) ? be2[j] : bfp[j - DOUTC];
  #pragma unroll
  for (int p = 0; p < 8; p++) s += part[((size_t)p * 44 + j) * 4096 + bn];
  if (j < DOUTC) out[(size_t)bn * DOUTC + j] = s;
  else out[(size_t)NBATCH * NN * DOUTC + (size_t)bn * DFC + (j - DOUTC)] = s;
}

// ------------------------------------------------------------------ launch
extern "C" void kernel_launch(void* const* d_in, const int* in_sizes, int n_in,
                              void* d_out, int out_size, void* d_ws, size_t ws_size,
                              hipStream_t stream)
{
  const float* xin = (const float*)d_in[0];
  const float* pre = (const float*)d_in[1];
  const float* adp = (const float*)d_in[2];
  const float* Wst = (const float*)d_in[3];
  const float* bst = (const float*)d_in[4];
  const float* Wf  = (const float*)d_in[5];
  const float* bf  = (const float*)d_in[6];
  const float* Wg  = (const float*)d_in[7];
  const float* bg  = (const float*)d_in[8];
  const float* Wr  = (const float*)d_in[9];
  const float* br  = (const float*)d_in[10];
  const float* Wsk = (const float*)d_in[11];
  const float* bsk = (const float*)d_in[12];
  const float* We1 = (const float*)d_in[13];
  const float* be1 = (const float*)d_in[14];
  const float* We2 = (const float*)d_in[15];
  const float* be2 = (const float*)d_in[16];
  const float* Wfp = (const float*)d_in[17];
  const float* bfp = (const float*)d_in[18];
  float* out = (float*)d_out;

  // workspace layout (floats); total 16,401,792 floats = 62.6 MiB
  float* ws    = (float*)d_ws;
  float* adj   = ws;                                   // 1008*1000
  float* X     = adj   + (size_t)NP * NN;              // 128*64*1000
  float* u_t   = X     + (size_t)128 * TFULL * NN;     // 128*30*1008
  float* xc63  = u_t   + (size_t)128 * 30 * NP;        // 128*1000
  float* skip  = xc63  + (size_t)128 * NN;             // 4000*256
  float* feat2 = skip  + (size_t)NBATCH * NN * CS;     // 4000*512
  float* We1T  = feat2 + (size_t)NBATCH * NN * CE;     // 256*512
  float* part  = u_t;  // head partials (8*44*4096 = 1.44M floats) alias u_t

  k_adj<<<dim3(NP), dim3(256), 0, stream>>>(adp, pre, adj);
  k_start<<<dim3(4, 31, NBATCH), dim3(256), 0, stream>>>(xin, Wst, bst, X);
  k_tr_we1<<<dim3(CE), dim3(256), 0, stream>>>(We1, We1T);

  const int dil[NL] = {1, 2, 4, 8, 1, 2, 4, 8};
  const int t0s[NL] = {34, 36, 40, 48, 49, 51, 55, 63}; // needed out-windows

  for (int i = 0; i < NL; i++) {
    const int d = dil[i], t0 = t0s[i], W = TFULL - t0;
    const int doU = (i < NL - 1) ? 1 : 0;   // layer 7: skip path only
    k_point<<<dim3(4, W, NBATCH), dim3(256), 0, stream>>>(
        X, u_t, xc63, Wf, bf, Wg, bg, Wr, i, d, t0, W, doU);
    k_skip<<<dim3(16, NBATCH), dim3(256), 0, stream>>>(xc63, Wsk, bsk, skip, i);
    if (doU) {
      const int M = 128 * W;
      const int NR = 2 * W, NC = 8;
      k_gemm<0><<<dim3(NR * NC), dim3(256), 0, stream>>>(
          u_t, adj, X, br + i * CR, M, NP, NP, NN, NN, W, t0, NR, NC);
    }
  }

  // head: feat2 = relu(skip @ We1^T + be1)  [4000 x 512]
  {
    const int NR = 63, NC = 4;
    k_gemm<1><<<dim3(NR * NC), dim3(256), 0, stream>>>(
        skip, We1T, feat2, be1, NBATCH * NN, CS, CS, CE, CE, 1, 0, NR, NC);
  }
  k_h2a<<<dim3(16, 8), dim3(256), 0, stream>>>(feat2, We2, Wfp, part);
  k_h2b<<<dim3(16, 44), dim3(256), 0, stream>>>(part, be2, bfp, out);
}